// Round 1
// baseline (215.607 us; speedup 1.0000x reference)
//
#include <hip/hip_runtime.h>

// NEAT windowed-DAG forward:
//   values[0:16] = x; for i in 0..511: v = tanh(dot(values[i:i+16], w[i]) + b[i]) * r[i]
//   out = values[464:528]  (i.e. nodes 448..511)
// One thread per batch element; 16-register circular window, unrolled by 16 so
// all window slots are static. Weights/bias/resp are wave-uniform -> scalar loads.

constexpr int kNIn    = 16;
constexpr int kFanin  = 16;
constexpr int kNodes  = 512;
constexpr int kNOut   = 64;
constexpr int kBatch  = 32768;
constexpr int kOutStartGroup = (kNodes - kNOut) / 16;  // group 28 (node 448)

__device__ __forceinline__ float fast_tanh(float x) {
    // tanh(x) = 1 - 2/(exp(2x)+1); exp(2x) = exp2(2*log2(e)*x)
    // Handles saturation cleanly: e=inf -> 1, e=0 -> -1. No NaNs.
    float e = __builtin_amdgcn_exp2f(x * 2.885390081777927f);
    return 1.0f - 2.0f * __builtin_amdgcn_rcpf(e + 1.0f);
}

__global__ __launch_bounds__(128) void neat_fwd(
    const float* __restrict__ x,      // [B, 16]
    const float* __restrict__ w,      // [512, 16]
    const float* __restrict__ bias,   // [512]
    const float* __restrict__ resp,   // [512]
    float* __restrict__ out)          // [B, 64]
{
    const int b = blockIdx.x * blockDim.x + threadIdx.x;

    // Circular window: win[s] holds values[g] with g == s (mod 16),
    // g in [i, i+16) just before computing node i.
    float win[16];
    const float4* __restrict__ x4 = reinterpret_cast<const float4*>(x) + (size_t)b * 4;
    float4 a0 = x4[0], a1 = x4[1], a2 = x4[2], a3 = x4[3];
    win[ 0] = a0.x; win[ 1] = a0.y; win[ 2] = a0.z; win[ 3] = a0.w;
    win[ 4] = a1.x; win[ 5] = a1.y; win[ 6] = a1.z; win[ 7] = a1.w;
    win[ 8] = a2.x; win[ 9] = a2.y; win[10] = a2.z; win[11] = a2.w;
    win[12] = a3.x; win[13] = a3.y; win[14] = a3.z; win[15] = a3.w;

    float* __restrict__ op = out + (size_t)b * kNOut;

    for (int g = 0; g < kNodes / 16; ++g) {
        const float* __restrict__ wg = w    + g * (16 * kFanin);
        const float* __restrict__ bg = bias + g * 16;
        const float* __restrict__ rg = resp + g * 16;
        #pragma unroll
        for (int k = 0; k < 16; ++k) {
            // node i = g*16 + k; reads window slots (k+j)&15 with weight w[i][j].
            // j=15 (the just-computed previous node) is last -> shortest dep chain.
            float acc = bg[k];
            const float* __restrict__ wr = wg + k * kFanin;
            #pragma unroll
            for (int j = 0; j < kFanin; ++j) {
                acc = fmaf(win[(k + j) & 15], wr[j], acc);
            }
            float v = fast_tanh(acc) * rg[k];
            win[k] = v;  // slot (16+i) & 15 == k
            if (g >= kOutStartGroup) {
                op[(g - kOutStartGroup) * 16 + k] = v;
            }
        }
    }
}

extern "C" void kernel_launch(void* const* d_in, const int* in_sizes, int n_in,
                              void* d_out, int out_size, void* d_ws, size_t ws_size,
                              hipStream_t stream) {
    const float* x    = (const float*)d_in[0];
    const float* w    = (const float*)d_in[1];
    const float* bias = (const float*)d_in[2];
    const float* resp = (const float*)d_in[3];
    float* out = (float*)d_out;
    // in_sizes[4] (src_idx) encodes the fixed windowed topology; hardcoded above.
    dim3 block(128);
    dim3 grid(kBatch / 128);   // 256 blocks -> 1 per CU, 2 waves/CU
    hipLaunchKernelGGL(neat_fwd, grid, block, 0, stream, x, w, bias, resp, out);
}